// Round 11
// baseline (187.797 us; speedup 1.0000x reference)
//
#include <hip/hip_runtime.h>

#define N_NODES  50000
#define F_IN     128
#define F_H      128
#define F_OUT    32
#define N_EDGES  800000
#define NEG_SLOPE 0.01f
#define NBUCKET   196            // ceil(50000/256) buckets of 256 nodes
#define EDGE_BLOCKS 784          // edge blocks for counting sort
#define EPB       1024           // edges per edge-block (784*1024 >= 800000)
#define GEMM1_BLOCKS 782         // ceil(50000/64) row tiles of 64
#define GEMM2_BLOCKS 391         // ceil(50000/128)
#define AGG1_PASS_BLOCKS 782     // ceil(50000/64) node-groups per column pass

typedef short bf16x8 __attribute__((ext_vector_type(8)));
typedef float f32x4  __attribute__((ext_vector_type(4)));

// ---- bf16 helpers (RTNE) ----
__device__ __forceinline__ float bf2f(unsigned short h) {
    return __uint_as_float(((unsigned)h) << 16);
}
__device__ __forceinline__ unsigned short f2bf(float f) {
    unsigned u = __float_as_uint(f);
    u += 0x7FFF + ((u >> 16) & 1);
    return (unsigned short)(u >> 16);
}
// unpack 2 bf16 from a uint (memory order: lo ushort first)
__device__ __forceinline__ float bflo(unsigned u) { return __uint_as_float(u << 16); }
__device__ __forceinline__ float bfhi(unsigned u) { return __uint_as_float(u & 0xFFFF0000u); }

// ===========================================================================
// Kernel 1: edge histogram (blocks [0,EDGE_BLOCKS)) fused with
//   MFMA GEMM1: yb = bf16(x @ W1)  (blocks [EDGE_BLOCKS, +GEMM1_BLOCKS))
// ===========================================================================
__global__ __launch_bounds__(256) void hist_gemm1_kernel(
    const int* __restrict__ dst, int* __restrict__ counts,
    const float* __restrict__ x, const float* __restrict__ W1,
    unsigned short* __restrict__ yb)
{
    __shared__ alignas(16) unsigned short Xl[64 * 136];   // 17.4 KB
    int b = blockIdx.x;
    int t = threadIdx.x;

    if (b < EDGE_BLOCKS) {
        int* hist = (int*)Xl;
        for (int i = t; i < NBUCKET; i += 256) hist[i] = 0;
        __syncthreads();
        int base = b * EPB;
        for (int r = 0; r < EPB / 256; ++r) {
            int e = base + r * 256 + t;
            if (e < N_EDGES) atomicAdd(&hist[dst[e] >> 8], 1);
        }
        __syncthreads();
        for (int i = t; i < NBUCKET; i += 256)
            counts[i * EDGE_BLOCKS + b] = hist[i];
        return;
    }

    int g  = b - EDGE_BLOCKS;
    int vb = g * 64;

    // Stage x-tile -> bf16 LDS (64 rows x 128 k, stride 136)
    for (int i4 = t; i4 < 2048; i4 += 256) {
        int flat = i4 * 4;
        int r = flat >> 7;
        int k = flat & 127;
        int v = vb + r;
        float4 xv = (v < N_NODES) ? *(const float4*)(x + (size_t)v * 128 + k)
                                  : make_float4(0.f, 0.f, 0.f, 0.f);
        ushort4 o;
        o.x = f2bf(xv.x); o.y = f2bf(xv.y); o.z = f2bf(xv.z); o.w = f2bf(xv.w);
        *(ushort4*)(Xl + r * 136 + k) = o;
    }

    int wv   = t >> 6;        // wave 0..3 -> cols [wv*32, wv*32+32)
    int lane = t & 63;
    int quad = lane >> 4;
    int lc   = lane & 15;
    int c0   = wv * 32;

    // B-fragments from fp32 W1 (in-register convert)
    bf16x8 bfr[2][4];
    for (int ct = 0; ct < 2; ++ct)
        for (int ks = 0; ks < 4; ++ks) {
            bf16x8 tmp;
            #pragma unroll
            for (int j = 0; j < 8; ++j)
                tmp[j] = (short)f2bf(W1[(ks * 32 + quad * 8 + j) * 128 + c0 + ct * 16 + lc]);
            bfr[ct][ks] = tmp;
        }

    __syncthreads();

    f32x4 acc[4][2];
    for (int rt = 0; rt < 4; ++rt)
        for (int ct = 0; ct < 2; ++ct)
            acc[rt][ct] = (f32x4){0.f, 0.f, 0.f, 0.f};

    for (int rt = 0; rt < 4; ++rt) {
        int row = rt * 16 + lc;
        #pragma unroll
        for (int ks = 0; ks < 4; ++ks) {
            bf16x8 af = *(const bf16x8*)(Xl + row * 136 + ks * 32 + quad * 8);
            acc[rt][0] = __builtin_amdgcn_mfma_f32_16x16x32_bf16(af, bfr[0][ks], acc[rt][0], 0, 0, 0);
            acc[rt][1] = __builtin_amdgcn_mfma_f32_16x16x32_bf16(af, bfr[1][ks], acc[rt][1], 0, 0, 0);
        }
    }

    for (int rt = 0; rt < 4; ++rt)
        for (int ct = 0; ct < 2; ++ct)
            #pragma unroll
            for (int r = 0; r < 4; ++r) {
                int grow = vb + rt * 16 + quad * 4 + r;
                if (grow < N_NODES)
                    yb[(size_t)grow * 128 + c0 + ct * 16 + lc] = f2bf(acc[rt][ct][r]);
            }
}

// ===========================================================================
// CSR build (zero global atomics)
// ===========================================================================
__global__ __launch_bounds__(256) void scan_cols_kernel(
    int* __restrict__ counts, int* __restrict__ bucket_total)
{
    __shared__ int c[256];
    int t = threadIdx.x;
    int carry = 0;
    for (int ch = 0; ch < (EDGE_BLOCKS + 255) / 256; ++ch) {
        int ci = ch * 256 + t;
        int cv = (ci < EDGE_BLOCKS) ? counts[blockIdx.x * EDGE_BLOCKS + ci] : 0;
        c[t] = cv;
        __syncthreads();
        for (int off = 1; off < 256; off <<= 1) {
            int a = c[t];
            int add = (t >= off) ? c[t - off] : 0;
            __syncthreads();
            c[t] = a + add;
            __syncthreads();
        }
        if (ci < EDGE_BLOCKS)
            counts[blockIdx.x * EDGE_BLOCKS + ci] = carry + c[t] - cv;
        carry += c[255];
        __syncthreads();
    }
    if (t == 0) bucket_total[blockIdx.x] = carry;
}

__global__ __launch_bounds__(256) void bin_kernel(
    const int* __restrict__ src, const int* __restrict__ dst,
    const int* __restrict__ rel, const int* __restrict__ bucket_total,
    unsigned int* __restrict__ bins)
{
    __shared__ int s[256];
    __shared__ int pos[NBUCKET];
    int blk = blockIdx.x;
    int t = threadIdx.x;
    int bt = (t < NBUCKET) ? bucket_total[t] : 0;
    s[t] = bt;
    __syncthreads();
    for (int off = 1; off < 256; off <<= 1) {
        int a = s[t];
        int add = (t >= off) ? s[t - off] : 0;
        __syncthreads();
        s[t] = a + add;
        __syncthreads();
    }
    if (t < NBUCKET)
        pos[t] = (s[t] - bt) + rel[t * EDGE_BLOCKS + blk];
    __syncthreads();
    int base = blk * EPB;
    for (int r = 0; r < EPB / 256; ++r) {
        int e = base + r * 256 + t;
        if (e < N_EDGES) {
            int d = dst[e];
            int sy = src[e];
            int p = atomicAdd(&pos[d >> 8], 1);
            bins[p] = ((unsigned)d << 16) | (unsigned)sy;
        }
    }
}

__global__ __launch_bounds__(256) void bucket_sort_kernel(
    const unsigned int* __restrict__ bins, const int* __restrict__ bucket_total,
    int* __restrict__ row_ptr, int* __restrict__ csr)
{
    __shared__ int s[256];
    __shared__ int cnt[256];
    __shared__ int cur[256];
    int b = blockIdx.x;
    int t = threadIdx.x;
    int bt = (t < NBUCKET) ? bucket_total[t] : 0;
    s[t] = bt;
    __syncthreads();
    for (int off = 1; off < 256; off <<= 1) {
        int a = s[t];
        int add = (t >= off) ? s[t - off] : 0;
        __syncthreads();
        s[t] = a + add;
        __syncthreads();
    }
    int beg = (b == 0) ? 0 : s[b - 1];
    int end = s[b];
    cnt[t] = 0;
    __syncthreads();
    for (int i = beg + t; i < end; i += 256)
        atomicAdd(&cnt[(bins[i] >> 16) & 255], 1);
    __syncthreads();
    int v = cnt[t];
    cur[t] = v;
    __syncthreads();
    for (int off = 1; off < 256; off <<= 1) {
        int a = cur[t];
        int add = (t >= off) ? cur[t - off] : 0;
        __syncthreads();
        cur[t] = a + add;
        __syncthreads();
    }
    int start = beg + cur[t] - v;
    int node = b * 256 + t;
    if (node < N_NODES) row_ptr[node] = start;
    cur[t] = start;
    if (b == 0 && t == 0) row_ptr[N_NODES] = N_EDGES;
    __syncthreads();
    for (int i = beg + t; i < end; i += 256) {
        unsigned w = bins[i];
        int dl = (w >> 16) & 255;
        int p = atomicAdd(&cur[dl], 1);
        csr[p] = (int)(w & 0xFFFFu);
    }
}

// ===========================================================================
// Layer-1 aggregate, COLUMN-SLICED for per-XCD L2 residency.
// 4 passes x 32 cols; per pass the gather slice is 3.2 MB (< 4 MB L2/XCD).
// Pass-major block order so slices are processed ~sequentially.
// Per node: 4 lanes x 8 cols (uint4 = 16B loads; 64B/neighbor contiguous).
// h1b[v,c] = bf16(leaky((yb[v,c]+Σ yb[u,c])/(deg+1)+b1[c]))
// ===========================================================================
__global__ __launch_bounds__(256) void aggregate128_kernel(
    const unsigned short* __restrict__ yb, const int* __restrict__ row_ptr,
    const int* __restrict__ csr, const float* __restrict__ b1,
    unsigned short* __restrict__ h1b)
{
    int pass = blockIdx.x / AGG1_PASS_BLOCKS;           // 0..3 (major order)
    int blk  = blockIdx.x - pass * AGG1_PASS_BLOCKS;
    int gw   = blk * 64 + (threadIdx.x >> 2);           // node
    int col  = pass * 32 + (threadIdx.x & 3) * 8;       // 8 cols per lane
    if (gw >= N_NODES) return;
    int beg = row_ptr[gw];
    int end = row_ptr[gw + 1];
    uint4 us = *(const uint4*)(yb + (size_t)gw * 128 + col);
    float a0 = bflo(us.x), a1 = bfhi(us.x), a2 = bflo(us.y), a3 = bfhi(us.y);
    float a4 = bflo(us.z), a5 = bfhi(us.z), a6 = bflo(us.w), a7 = bfhi(us.w);
    float c0 = 0.f, c1 = 0.f, c2 = 0.f, c3 = 0.f;
    float c4 = 0.f, c5 = 0.f, c6 = 0.f, c7 = 0.f;
    int p = beg;
    for (; p + 1 < end; p += 2) {
        int s0 = csr[p], s1 = csr[p + 1];
        uint4 u0 = *(const uint4*)(yb + (size_t)s0 * 128 + col);
        uint4 u1 = *(const uint4*)(yb + (size_t)s1 * 128 + col);
        a0 += bflo(u0.x); a1 += bfhi(u0.x); a2 += bflo(u0.y); a3 += bfhi(u0.y);
        a4 += bflo(u0.z); a5 += bfhi(u0.z); a6 += bflo(u0.w); a7 += bfhi(u0.w);
        c0 += bflo(u1.x); c1 += bfhi(u1.x); c2 += bflo(u1.y); c3 += bfhi(u1.y);
        c4 += bflo(u1.z); c5 += bfhi(u1.z); c6 += bflo(u1.w); c7 += bfhi(u1.w);
    }
    if (p < end) {
        int s0 = csr[p];
        uint4 u0 = *(const uint4*)(yb + (size_t)s0 * 128 + col);
        a0 += bflo(u0.x); a1 += bfhi(u0.x); a2 += bflo(u0.y); a3 += bfhi(u0.y);
        a4 += bflo(u0.z); a5 += bfhi(u0.z); a6 += bflo(u0.w); a7 += bfhi(u0.w);
    }
    float rec = 1.0f / (float)(end - beg + 1);
    float4 bb0 = *(const float4*)(b1 + col);
    float4 bb1 = *(const float4*)(b1 + col + 4);
    float v0 = (a0 + c0) * rec + bb0.x;
    float v1 = (a1 + c1) * rec + bb0.y;
    float v2 = (a2 + c2) * rec + bb0.z;
    float v3 = (a3 + c3) * rec + bb0.w;
    float v4 = (a4 + c4) * rec + bb1.x;
    float v5 = (a5 + c5) * rec + bb1.y;
    float v6 = (a6 + c6) * rec + bb1.z;
    float v7 = (a7 + c7) * rec + bb1.w;
    v0 = (v0 >= 0.f) ? v0 : NEG_SLOPE * v0;
    v1 = (v1 >= 0.f) ? v1 : NEG_SLOPE * v1;
    v2 = (v2 >= 0.f) ? v2 : NEG_SLOPE * v2;
    v3 = (v3 >= 0.f) ? v3 : NEG_SLOPE * v3;
    v4 = (v4 >= 0.f) ? v4 : NEG_SLOPE * v4;
    v5 = (v5 >= 0.f) ? v5 : NEG_SLOPE * v5;
    v6 = (v6 >= 0.f) ? v6 : NEG_SLOPE * v6;
    v7 = (v7 >= 0.f) ? v7 : NEG_SLOPE * v7;
    uint4 o;
    o.x = (unsigned)f2bf(v0) | ((unsigned)f2bf(v1) << 16);
    o.y = (unsigned)f2bf(v2) | ((unsigned)f2bf(v3) << 16);
    o.z = (unsigned)f2bf(v4) | ((unsigned)f2bf(v5) << 16);
    o.w = (unsigned)f2bf(v6) | ((unsigned)f2bf(v7) << 16);
    *(uint4*)(h1b + (size_t)gw * 128 + col) = o;
}

// 4 lanes/node x 8 cols; zb table 3.2 MB (L2-resident). out fp32.
__global__ __launch_bounds__(256) void aggregate32_kernel(
    const unsigned short* __restrict__ zb, const int* __restrict__ row_ptr,
    const int* __restrict__ csr, const float* __restrict__ b2,
    float* __restrict__ out)
{
    int g  = (blockIdx.x * 256 + threadIdx.x) >> 2;
    int l8 = (threadIdx.x & 3) * 8;
    if (g >= N_NODES) return;
    int beg = row_ptr[g];
    int end = row_ptr[g + 1];
    uint4 us = *(const uint4*)(zb + (size_t)g * 32 + l8);
    float a0 = bflo(us.x), a1 = bfhi(us.x), a2 = bflo(us.y), a3 = bfhi(us.y);
    float a4 = bflo(us.z), a5 = bfhi(us.z), a6 = bflo(us.w), a7 = bfhi(us.w);
    float c0 = 0.f, c1 = 0.f, c2 = 0.f, c3 = 0.f;
    float c4 = 0.f, c5 = 0.f, c6 = 0.f, c7 = 0.f;
    int p = beg;
    for (; p + 1 < end; p += 2) {
        int s0 = csr[p], s1 = csr[p + 1];
        uint4 u0 = *(const uint4*)(zb + (size_t)s0 * 32 + l8);
        uint4 u1 = *(const uint4*)(zb + (size_t)s1 * 32 + l8);
        a0 += bflo(u0.x); a1 += bfhi(u0.x); a2 += bflo(u0.y); a3 += bfhi(u0.y);
        a4 += bflo(u0.z); a5 += bfhi(u0.z); a6 += bflo(u0.w); a7 += bfhi(u0.w);
        c0 += bflo(u1.x); c1 += bfhi(u1.x); c2 += bflo(u1.y); c3 += bfhi(u1.y);
        c4 += bflo(u1.z); c5 += bfhi(u1.z); c6 += bflo(u1.w); c7 += bfhi(u1.w);
    }
    if (p < end) {
        int s0 = csr[p];
        uint4 u0 = *(const uint4*)(zb + (size_t)s0 * 32 + l8);
        a0 += bflo(u0.x); a1 += bfhi(u0.x); a2 += bflo(u0.y); a3 += bfhi(u0.y);
        a4 += bflo(u0.z); a5 += bfhi(u0.z); a6 += bflo(u0.w); a7 += bfhi(u0.w);
    }
    float rec = 1.0f / (float)(end - beg + 1);
    float4 bb0 = *(const float4*)(b2 + l8);
    float4 bb1 = *(const float4*)(b2 + l8 + 4);
    float4 o0, o1;
    o0.x = (a0 + c0) * rec + bb0.x;
    o0.y = (a1 + c1) * rec + bb0.y;
    o0.z = (a2 + c2) * rec + bb0.z;
    o0.w = (a3 + c3) * rec + bb0.w;
    o1.x = (a4 + c4) * rec + bb1.x;
    o1.y = (a5 + c5) * rec + bb1.y;
    o1.z = (a6 + c6) * rec + bb1.z;
    o1.w = (a7 + c7) * rec + bb1.w;
    *(float4*)(out + (size_t)g * 32 + l8) = o0;
    *(float4*)(out + (size_t)g * 32 + l8 + 4) = o1;
}

// ===========================================================================
// GEMM2 via MFMA, zero LDS: zb = bf16(h1b @ W2)  (W2 fp32, in-reg convert)
// ===========================================================================
__global__ __launch_bounds__(256) void gemm2z_kernel(
    const unsigned short* __restrict__ h1b,
    const float* __restrict__ W2, unsigned short* __restrict__ zb)
{
    int t    = threadIdx.x;
    int wv   = t >> 6;
    int lane = t & 63;
    int quad = lane >> 4;
    int lc   = lane & 15;

    bf16x8 bfr[2][4];
    for (int ct = 0; ct < 2; ++ct)
        for (int ks = 0; ks < 4; ++ks) {
            bf16x8 tmp;
            #pragma unroll
            for (int j = 0; j < 8; ++j)
                tmp[j] = (short)f2bf(W2[(ks * 32 + quad * 8 + j) * 32 + ct * 16 + lc]);
            bfr[ct][ks] = tmp;
        }

    f32x4 acc[2][2];
    for (int rt = 0; rt < 2; ++rt)
        for (int ct = 0; ct < 2; ++ct)
            acc[rt][ct] = (f32x4){0.f, 0.f, 0.f, 0.f};

    int vb = blockIdx.x * 128 + wv * 32;
    for (int rt = 0; rt < 2; ++rt) {
        int row = vb + rt * 16 + lc;
        int vrow = (row < N_NODES) ? row : 0;
        #pragma unroll
        for (int ks = 0; ks < 4; ++ks) {
            bf16x8 af = *(const bf16x8*)(h1b + (size_t)vrow * 128 + ks * 32 + quad * 8);
            acc[rt][0] = __builtin_amdgcn_mfma_f32_16x16x32_bf16(af, bfr[0][ks], acc[rt][0], 0, 0, 0);
            acc[rt][1] = __builtin_amdgcn_mfma_f32_16x16x32_bf16(af, bfr[1][ks], acc[rt][1], 0, 0, 0);
        }
    }

    for (int rt = 0; rt < 2; ++rt)
        for (int ct = 0; ct < 2; ++ct)
            #pragma unroll
            for (int r = 0; r < 4; ++r) {
                int grow = vb + rt * 16 + quad * 4 + r;
                if (grow < N_NODES)
                    zb[(size_t)grow * 32 + ct * 16 + lc] = f2bf(acc[rt][ct][r]);
            }
}

// ===========================================================================
// FALLBACK PATH (ws too small): atomic scatter + fp32 GEMMs
// ===========================================================================
__global__ __launch_bounds__(256) void scatter_kernel(
    const float* __restrict__ x, const int* __restrict__ src,
    const int* __restrict__ dst, float* __restrict__ msg,
    float* __restrict__ deg, int nE)
{
    int tid  = blockIdx.x * 256 + threadIdx.x;
    int e    = tid >> 5;
    int lane = tid & 31;
    if (e >= nE) return;
    int s = src[e];
    int d = dst[e];
    if (deg != nullptr && lane == 0) atomicAdd(&deg[d], 1.0f);
    float4 v = *(const float4*)(x + (size_t)s * F_IN + lane * 4);
    float* mp = msg + (size_t)d * F_IN + lane * 4;
    atomicAdd(mp + 0, v.x);
    atomicAdd(mp + 1, v.y);
    atomicAdd(mp + 2, v.z);
    atomicAdd(mp + 3, v.w);
}

__global__ __launch_bounds__(256) void normalize_kernel(
    const float* __restrict__ self, const float* __restrict__ deg,
    float* __restrict__ msg)
{
    int idx = blockIdx.x * 256 + threadIdx.x;
    int v = idx >> 5;
    int c = (idx & 31) * 4;
    if (v >= N_NODES) return;
    float rec = 1.0f / (deg[v] + 1.0f);
    float4 m = *(const float4*)(msg  + (size_t)v * 128 + c);
    float4 s = *(const float4*)(self + (size_t)v * 128 + c);
    m.x = (m.x + s.x) * rec;
    m.y = (m.y + s.y) * rec;
    m.z = (m.z + s.z) * rec;
    m.w = (m.w + s.w) * rec;
    *(float4*)(msg + (size_t)v * 128 + c) = m;
}

__global__ __launch_bounds__(256) void gemm1_kernel(
    const float* __restrict__ msg, const float* __restrict__ W,
    const float* __restrict__ b, float* __restrict__ h)
{
    __shared__ float Wl[128 * 68];
    __shared__ float Rl[32 * 132];
    int t     = threadIdx.x;
    int vb    = blockIdx.x * 32;
    int jbase = blockIdx.y * 64;
    for (int i4 = t; i4 < 2048; i4 += 256) {
        int flat = i4 * 4;
        int k  = flat >> 6;
        int jj = flat & 63;
        *(float4*)(Wl + k * 68 + jj) = *(const float4*)(W + k * F_H + jbase + jj);
    }
    for (int i4 = t; i4 < 1024; i4 += 256) {
        int flat = i4 * 4;
        int r = flat >> 7;
        int k = flat & 127;
        int v = vb + r;
        float4 sv = (v < N_NODES) ? *(const float4*)(msg + (size_t)v * F_IN + k)
                                  : make_float4(0.f, 0.f, 0.f, 0.f);
        *(float4*)(Rl + r * 132 + k) = sv;
    }
    __syncthreads();
    int j0 = (t & 15) * 4;
    int r0 = (t >> 4) * 2;
    float acc[2][4] = {{0.f,0.f,0.f,0.f},{0.f,0.f,0.f,0.f}};
    for (int k = 0; k < 128; ++k) {
        float4 w = *(const float4*)(Wl + k * 68 + j0);
        float s0 = Rl[(r0    ) * 132 + k];
        float s1 = Rl[(r0 + 1) * 132 + k];
        acc[0][0] += s0 * w.x; acc[0][1] += s0 * w.y;
        acc[0][2] += s0 * w.z; acc[0][3] += s0 * w.w;
        acc[1][0] += s1 * w.x; acc[1][1] += s1 * w.y;
        acc[1][2] += s1 * w.z; acc[1][3] += s1 * w.w;
    }
    for (int i = 0; i < 2; ++i) {
        int v = vb + r0 + i;
        if (v >= N_NODES) continue;
        float4 o;
        o.x = acc[i][0] + b[jbase + j0 + 0];
        o.y = acc[i][1] + b[jbase + j0 + 1];
        o.z = acc[i][2] + b[jbase + j0 + 2];
        o.w = acc[i][3] + b[jbase + j0 + 3];
        o.x = (o.x >= 0.f) ? o.x : NEG_SLOPE * o.x;
        o.y = (o.y >= 0.f) ? o.y : NEG_SLOPE * o.y;
        o.z = (o.z >= 0.f) ? o.z : NEG_SLOPE * o.z;
        o.w = (o.w >= 0.f) ? o.w : NEG_SLOPE * o.w;
        *(float4*)(h + (size_t)v * F_H + jbase + j0) = o;
    }
}

__global__ __launch_bounds__(256) void gemm2_kernel(
    const float* __restrict__ msg, const float* __restrict__ W,
    const float* __restrict__ b, float* __restrict__ out)
{
    __shared__ float Wl[128 * 36];
    __shared__ float Rl[64 * 132];
    int t  = threadIdx.x;
    int vb = blockIdx.x * 64;
    for (int i4 = t; i4 < 1024; i4 += 256) {
        int flat = i4 * 4;
        int k  = flat >> 5;
        int jj = flat & 31;
        *(float4*)(Wl + k * 36 + jj) = *(const float4*)(W + k * F_OUT + jj);
    }
    for (int i4 = t; i4 < 2048; i4 += 256) {
        int flat = i4 * 4;
        int r = flat >> 7;
        int k = flat & 127;
        int v = vb + r;
        float4 sv = (v < N_NODES) ? *(const float4*)(msg + (size_t)v * F_H + k)
                                  : make_float4(0.f, 0.f, 0.f, 0.f);
        *(float4*)(Rl + r * 132 + k) = sv;
    }
    __syncthreads();
    int j0 = (t & 7) * 4;
    int r0 = (t >> 3) * 2;
    float acc[2][4] = {{0.f,0.f,0.f,0.f},{0.f,0.f,0.f,0.f}};
    for (int k = 0; k < 128; ++k) {
        float4 w = *(const float4*)(Wl + k * 36 + j0);
        float s0 = Rl[(r0    ) * 132 + k];
        float s1 = Rl[(r0 + 1) * 132 + k];
        acc[0][0] += s0 * w.x; acc[0][1] += s0 * w.y;
        acc[0][2] += s0 * w.z; acc[0][3] += s0 * w.w;
        acc[1][0] += s1 * w.x; acc[1][1] += s1 * w.y;
        acc[1][2] += s1 * w.z; acc[1][3] += s1 * w.w;
    }
    for (int i = 0; i < 2; ++i) {
        int v = vb + r0 + i;
        if (v >= N_NODES) continue;
        float4 o;
        o.x = acc[i][0] + b[j0 + 0];
        o.y = acc[i][1] + b[j0 + 1];
        o.z = acc[i][2] + b[j0 + 2];
        o.w = acc[i][3] + b[j0 + 3];
        *(float4*)(out + (size_t)v * F_OUT + j0) = o;
    }
}

// ===========================================================================
// Launch
// ===========================================================================
extern "C" void kernel_launch(void* const* d_in, const int* in_sizes, int n_in,
                              void* d_out, int out_size, void* d_ws, size_t ws_size,
                              hipStream_t stream)
{
    const float* x     = (const float*)d_in[0];
    const int*   edges = (const int*)d_in[1];
    const float* W1    = (const float*)d_in[2];
    const float* b1    = (const float*)d_in[3];
    const float* W2    = (const float*)d_in[4];
    const float* b2    = (const float*)d_in[5];
    float* out = (float*)d_out;

    const int* src = edges;
    const int* dst = edges + N_EDGES;

    const size_t INT_WORDS = 256ull + 50432ull + 800000ull + 153664ull + 800000ull;
    const size_t SHORTS = 6400000ull + 6400000ull + 1600000ull;
    const size_t FAST_BYTES = INT_WORDS * 4 + SHORTS * 2;   // ~36 MB

    if (ws_size >= FAST_BYTES) {
        // ---- fast path layout ----
        int*   bucket_total = (int*)d_ws;                      // [256]
        int*   row_ptr      = bucket_total + 256;              // [50432]
        int*   csr          = row_ptr + 50432;                 // [800000]
        int*   counts       = csr + 800000;                    // [153664]
        unsigned int* bins  = (unsigned int*)(counts + 153664);// [800000]
        unsigned short* yb  = (unsigned short*)(bins + 800000);// [6.4M]
        unsigned short* h1b = yb + 6400000;                    // [6.4M]
        unsigned short* zb  = h1b + 6400000;                   // [1.6M]

        // 1. Fused: edge histogram + MFMA y = x@W1 (bf16)
        hist_gemm1_kernel<<<EDGE_BLOCKS + GEMM1_BLOCKS, 256, 0, stream>>>(
            dst, counts, x, W1, yb);
        // 2-4. CSR build (no global atomics, no memsets)
        scan_cols_kernel<<<NBUCKET, 256, 0, stream>>>(counts, bucket_total);
        bin_kernel<<<EDGE_BLOCKS, 256, 0, stream>>>(src, dst, counts,
                                                    bucket_total, bins);
        bucket_sort_kernel<<<NBUCKET, 256, 0, stream>>>(bins, bucket_total,
                                                        row_ptr, csr);
        // 5. Layer-1 aggregate, 4 column-sliced passes (L2-resident slices)
        aggregate128_kernel<<<AGG1_PASS_BLOCKS * 4, 256, 0, stream>>>(
            yb, row_ptr, csr, b1, h1b);
        // 6. z = h1 @ W2 via MFMA (bf16 in/out, no LDS)
        gemm2z_kernel<<<GEMM2_BLOCKS, 256, 0, stream>>>(h1b, W2, zb);
        // 7. Layer-2 aggregate w/ fused bias, fp32 out
        aggregate32_kernel<<<(N_NODES * 4 + 255) / 256, 256, 0, stream>>>(
            zb, row_ptr, csr, b2, out);
    } else {
        // ---- fallback: atomic scatter (fp32 end-to-end) ----
        float* deg = (float*)d_ws;
        float* msg = deg + 50176;
        float* h1  = msg + (size_t)N_NODES * F_H;

        hipMemsetAsync(d_ws, 0, (50176 + (size_t)N_NODES * F_H) * sizeof(float), stream);
        int sb = (N_EDGES * 32 + 255) / 256;
        int nb = (N_NODES * 32 + 255) / 256;

        scatter_kernel<<<sb, 256, 0, stream>>>(x, src, dst, msg, deg, N_EDGES);
        normalize_kernel<<<nb, 256, 0, stream>>>(x, deg, msg);
        gemm1_kernel<<<dim3((N_NODES + 31) / 32, 2), 256, 0, stream>>>(msg, W1, b1, h1);

        hipMemsetAsync(msg, 0, (size_t)N_NODES * F_H * sizeof(float), stream);
        scatter_kernel<<<sb, 256, 0, stream>>>(h1, src, dst, msg, nullptr, N_EDGES);
        normalize_kernel<<<nb, 256, 0, stream>>>(h1, deg, msg);
        gemm2_kernel<<<(N_NODES + 63) / 64, 256, 0, stream>>>(msg, W2, b2, out);
    }
}

// Round 12
// 169.630 us; speedup vs baseline: 1.1071x; 1.1071x over previous
//
#include <hip/hip_runtime.h>

#define N_NODES  50000
#define F_IN     128
#define F_H      128
#define F_OUT    32
#define N_EDGES  800000
#define NEG_SLOPE 0.01f
#define NBUCKET   196            // ceil(50000/256) buckets of 256 nodes
#define EDGE_BLOCKS 784          // edge blocks for counting sort
#define EPB       1024           // edges per edge-block (784*1024 >= 800000)
#define GEMM1_BLOCKS 782         // ceil(50000/64) row tiles of 64
#define GEMM2_BLOCKS 391         // ceil(50000/128)

typedef short bf16x8 __attribute__((ext_vector_type(8)));
typedef float f32x4  __attribute__((ext_vector_type(4)));

// ---- bf16 helpers (RTNE) ----
__device__ __forceinline__ float bf2f(unsigned short h) {
    return __uint_as_float(((unsigned)h) << 16);
}
__device__ __forceinline__ unsigned short f2bf(float f) {
    unsigned u = __float_as_uint(f);
    u += 0x7FFF + ((u >> 16) & 1);
    return (unsigned short)(u >> 16);
}
// unpack 2 bf16 from a uint (memory order: lo ushort first)
__device__ __forceinline__ float bflo(unsigned u) { return __uint_as_float(u << 16); }
__device__ __forceinline__ float bfhi(unsigned u) { return __uint_as_float(u & 0xFFFF0000u); }

// ===========================================================================
// Kernel 1: edge histogram (blocks [0,EDGE_BLOCKS)) fused with
//   MFMA GEMM1: yb = bf16(x @ W1)  (blocks [EDGE_BLOCKS, +GEMM1_BLOCKS))
// ===========================================================================
__global__ __launch_bounds__(256) void hist_gemm1_kernel(
    const int* __restrict__ dst, int* __restrict__ counts,
    const float* __restrict__ x, const float* __restrict__ W1,
    unsigned short* __restrict__ yb)
{
    __shared__ alignas(16) unsigned short Xl[64 * 136];   // 17.4 KB
    int b = blockIdx.x;
    int t = threadIdx.x;

    if (b < EDGE_BLOCKS) {
        int* hist = (int*)Xl;
        for (int i = t; i < NBUCKET; i += 256) hist[i] = 0;
        __syncthreads();
        int base = b * EPB;
        for (int r = 0; r < EPB / 256; ++r) {
            int e = base + r * 256 + t;
            if (e < N_EDGES) atomicAdd(&hist[dst[e] >> 8], 1);
        }
        __syncthreads();
        for (int i = t; i < NBUCKET; i += 256)
            counts[i * EDGE_BLOCKS + b] = hist[i];
        return;
    }

    int g  = b - EDGE_BLOCKS;
    int vb = g * 64;

    // Stage x-tile -> bf16 LDS (64 rows x 128 k, stride 136)
    for (int i4 = t; i4 < 2048; i4 += 256) {
        int flat = i4 * 4;
        int r = flat >> 7;
        int k = flat & 127;
        int v = vb + r;
        float4 xv = (v < N_NODES) ? *(const float4*)(x + (size_t)v * 128 + k)
                                  : make_float4(0.f, 0.f, 0.f, 0.f);
        ushort4 o;
        o.x = f2bf(xv.x); o.y = f2bf(xv.y); o.z = f2bf(xv.z); o.w = f2bf(xv.w);
        *(ushort4*)(Xl + r * 136 + k) = o;
    }

    int wv   = t >> 6;        // wave 0..3 -> cols [wv*32, wv*32+32)
    int lane = t & 63;
    int quad = lane >> 4;
    int lc   = lane & 15;
    int c0   = wv * 32;

    // B-fragments from fp32 W1 (in-register convert)
    bf16x8 bfr[2][4];
    for (int ct = 0; ct < 2; ++ct)
        for (int ks = 0; ks < 4; ++ks) {
            bf16x8 tmp;
            #pragma unroll
            for (int j = 0; j < 8; ++j)
                tmp[j] = (short)f2bf(W1[(ks * 32 + quad * 8 + j) * 128 + c0 + ct * 16 + lc]);
            bfr[ct][ks] = tmp;
        }

    __syncthreads();

    f32x4 acc[4][2];
    for (int rt = 0; rt < 4; ++rt)
        for (int ct = 0; ct < 2; ++ct)
            acc[rt][ct] = (f32x4){0.f, 0.f, 0.f, 0.f};

    for (int rt = 0; rt < 4; ++rt) {
        int row = rt * 16 + lc;
        #pragma unroll
        for (int ks = 0; ks < 4; ++ks) {
            bf16x8 af = *(const bf16x8*)(Xl + row * 136 + ks * 32 + quad * 8);
            acc[rt][0] = __builtin_amdgcn_mfma_f32_16x16x32_bf16(af, bfr[0][ks], acc[rt][0], 0, 0, 0);
            acc[rt][1] = __builtin_amdgcn_mfma_f32_16x16x32_bf16(af, bfr[1][ks], acc[rt][1], 0, 0, 0);
        }
    }

    for (int rt = 0; rt < 4; ++rt)
        for (int ct = 0; ct < 2; ++ct)
            #pragma unroll
            for (int r = 0; r < 4; ++r) {
                int grow = vb + rt * 16 + quad * 4 + r;
                if (grow < N_NODES)
                    yb[(size_t)grow * 128 + c0 + ct * 16 + lc] = f2bf(acc[rt][ct][r]);
            }
}

// ===========================================================================
// CSR build (zero global atomics)
// ===========================================================================
__global__ __launch_bounds__(256) void scan_cols_kernel(
    int* __restrict__ counts, int* __restrict__ bucket_total)
{
    __shared__ int c[256];
    int t = threadIdx.x;
    int carry = 0;
    for (int ch = 0; ch < (EDGE_BLOCKS + 255) / 256; ++ch) {
        int ci = ch * 256 + t;
        int cv = (ci < EDGE_BLOCKS) ? counts[blockIdx.x * EDGE_BLOCKS + ci] : 0;
        c[t] = cv;
        __syncthreads();
        for (int off = 1; off < 256; off <<= 1) {
            int a = c[t];
            int add = (t >= off) ? c[t - off] : 0;
            __syncthreads();
            c[t] = a + add;
            __syncthreads();
        }
        if (ci < EDGE_BLOCKS)
            counts[blockIdx.x * EDGE_BLOCKS + ci] = carry + c[t] - cv;
        carry += c[255];
        __syncthreads();
    }
    if (t == 0) bucket_total[blockIdx.x] = carry;
}

__global__ __launch_bounds__(256) void bin_kernel(
    const int* __restrict__ src, const int* __restrict__ dst,
    const int* __restrict__ rel, const int* __restrict__ bucket_total,
    unsigned int* __restrict__ bins)
{
    __shared__ int s[256];
    __shared__ int pos[NBUCKET];
    int blk = blockIdx.x;
    int t = threadIdx.x;
    int bt = (t < NBUCKET) ? bucket_total[t] : 0;
    s[t] = bt;
    __syncthreads();
    for (int off = 1; off < 256; off <<= 1) {
        int a = s[t];
        int add = (t >= off) ? s[t - off] : 0;
        __syncthreads();
        s[t] = a + add;
        __syncthreads();
    }
    if (t < NBUCKET)
        pos[t] = (s[t] - bt) + rel[t * EDGE_BLOCKS + blk];
    __syncthreads();
    int base = blk * EPB;
    for (int r = 0; r < EPB / 256; ++r) {
        int e = base + r * 256 + t;
        if (e < N_EDGES) {
            int d = dst[e];
            int sy = src[e];
            int p = atomicAdd(&pos[d >> 8], 1);
            bins[p] = ((unsigned)d << 16) | (unsigned)sy;
        }
    }
}

__global__ __launch_bounds__(256) void bucket_sort_kernel(
    const unsigned int* __restrict__ bins, const int* __restrict__ bucket_total,
    int* __restrict__ row_ptr, int* __restrict__ csr)
{
    __shared__ int s[256];
    __shared__ int cnt[256];
    __shared__ int cur[256];
    int b = blockIdx.x;
    int t = threadIdx.x;
    int bt = (t < NBUCKET) ? bucket_total[t] : 0;
    s[t] = bt;
    __syncthreads();
    for (int off = 1; off < 256; off <<= 1) {
        int a = s[t];
        int add = (t >= off) ? s[t - off] : 0;
        __syncthreads();
        s[t] = a + add;
        __syncthreads();
    }
    int beg = (b == 0) ? 0 : s[b - 1];
    int end = s[b];
    cnt[t] = 0;
    __syncthreads();
    for (int i = beg + t; i < end; i += 256)
        atomicAdd(&cnt[(bins[i] >> 16) & 255], 1);
    __syncthreads();
    int v = cnt[t];
    cur[t] = v;
    __syncthreads();
    for (int off = 1; off < 256; off <<= 1) {
        int a = cur[t];
        int add = (t >= off) ? cur[t - off] : 0;
        __syncthreads();
        cur[t] = a + add;
        __syncthreads();
    }
    int start = beg + cur[t] - v;
    int node = b * 256 + t;
    if (node < N_NODES) row_ptr[node] = start;
    cur[t] = start;
    if (b == 0 && t == 0) row_ptr[N_NODES] = N_EDGES;
    __syncthreads();
    for (int i = beg + t; i < end; i += 256) {
        unsigned w = bins[i];
        int dl = (w >> 16) & 255;
        int p = atomicAdd(&cur[dl], 1);
        csr[p] = (int)(w & 0xFFFFu);
    }
}

// ===========================================================================
// Aggregates — bf16 tables, 16B/lane FULL-ROW gathers (R10 form; the R11
// column-slicing experiment multiplied line fetches 4x — reverted).
// ===========================================================================

// 16 lanes/node x 8 cols (uint4 = 16B): row read = 256B contiguous.
// h1b[v] = bf16(leaky((yb[v]+Σ yb[u])/(deg+1)+b1))
__global__ __launch_bounds__(256) void aggregate128_kernel(
    const unsigned short* __restrict__ yb, const int* __restrict__ row_ptr,
    const int* __restrict__ csr, const float* __restrict__ b1,
    unsigned short* __restrict__ h1b)
{
    int gw = (blockIdx.x * 256 + threadIdx.x) >> 4;
    int l8 = (threadIdx.x & 15) * 8;
    if (gw >= N_NODES) return;
    int beg = row_ptr[gw];
    int end = row_ptr[gw + 1];
    uint4 us = *(const uint4*)(yb + (size_t)gw * 128 + l8);
    float a0 = bflo(us.x), a1 = bfhi(us.x), a2 = bflo(us.y), a3 = bfhi(us.y);
    float a4 = bflo(us.z), a5 = bfhi(us.z), a6 = bflo(us.w), a7 = bfhi(us.w);
    float c0 = 0.f, c1 = 0.f, c2 = 0.f, c3 = 0.f;
    float c4 = 0.f, c5 = 0.f, c6 = 0.f, c7 = 0.f;
    int p = beg;
    for (; p + 1 < end; p += 2) {
        int s0 = csr[p], s1 = csr[p + 1];
        uint4 u0 = *(const uint4*)(yb + (size_t)s0 * 128 + l8);
        uint4 u1 = *(const uint4*)(yb + (size_t)s1 * 128 + l8);
        a0 += bflo(u0.x); a1 += bfhi(u0.x); a2 += bflo(u0.y); a3 += bfhi(u0.y);
        a4 += bflo(u0.z); a5 += bfhi(u0.z); a6 += bflo(u0.w); a7 += bfhi(u0.w);
        c0 += bflo(u1.x); c1 += bfhi(u1.x); c2 += bflo(u1.y); c3 += bfhi(u1.y);
        c4 += bflo(u1.z); c5 += bfhi(u1.z); c6 += bflo(u1.w); c7 += bfhi(u1.w);
    }
    if (p < end) {
        int s0 = csr[p];
        uint4 u0 = *(const uint4*)(yb + (size_t)s0 * 128 + l8);
        a0 += bflo(u0.x); a1 += bfhi(u0.x); a2 += bflo(u0.y); a3 += bfhi(u0.y);
        a4 += bflo(u0.z); a5 += bfhi(u0.z); a6 += bflo(u0.w); a7 += bfhi(u0.w);
    }
    float rec = 1.0f / (float)(end - beg + 1);
    float4 bb0 = *(const float4*)(b1 + l8);
    float4 bb1 = *(const float4*)(b1 + l8 + 4);
    float v0 = (a0 + c0) * rec + bb0.x;
    float v1 = (a1 + c1) * rec + bb0.y;
    float v2 = (a2 + c2) * rec + bb0.z;
    float v3 = (a3 + c3) * rec + bb0.w;
    float v4 = (a4 + c4) * rec + bb1.x;
    float v5 = (a5 + c5) * rec + bb1.y;
    float v6 = (a6 + c6) * rec + bb1.z;
    float v7 = (a7 + c7) * rec + bb1.w;
    v0 = (v0 >= 0.f) ? v0 : NEG_SLOPE * v0;
    v1 = (v1 >= 0.f) ? v1 : NEG_SLOPE * v1;
    v2 = (v2 >= 0.f) ? v2 : NEG_SLOPE * v2;
    v3 = (v3 >= 0.f) ? v3 : NEG_SLOPE * v3;
    v4 = (v4 >= 0.f) ? v4 : NEG_SLOPE * v4;
    v5 = (v5 >= 0.f) ? v5 : NEG_SLOPE * v5;
    v6 = (v6 >= 0.f) ? v6 : NEG_SLOPE * v6;
    v7 = (v7 >= 0.f) ? v7 : NEG_SLOPE * v7;
    uint4 o;
    o.x = (unsigned)f2bf(v0) | ((unsigned)f2bf(v1) << 16);
    o.y = (unsigned)f2bf(v2) | ((unsigned)f2bf(v3) << 16);
    o.z = (unsigned)f2bf(v4) | ((unsigned)f2bf(v5) << 16);
    o.w = (unsigned)f2bf(v6) | ((unsigned)f2bf(v7) << 16);
    *(uint4*)(h1b + (size_t)gw * 128 + l8) = o;
}

// 4 lanes/node x 8 cols; zb table 3.2 MB. out fp32.
__global__ __launch_bounds__(256) void aggregate32_kernel(
    const unsigned short* __restrict__ zb, const int* __restrict__ row_ptr,
    const int* __restrict__ csr, const float* __restrict__ b2,
    float* __restrict__ out)
{
    int g  = (blockIdx.x * 256 + threadIdx.x) >> 2;
    int l8 = (threadIdx.x & 3) * 8;
    if (g >= N_NODES) return;
    int beg = row_ptr[g];
    int end = row_ptr[g + 1];
    uint4 us = *(const uint4*)(zb + (size_t)g * 32 + l8);
    float a0 = bflo(us.x), a1 = bfhi(us.x), a2 = bflo(us.y), a3 = bfhi(us.y);
    float a4 = bflo(us.z), a5 = bfhi(us.z), a6 = bflo(us.w), a7 = bfhi(us.w);
    float c0 = 0.f, c1 = 0.f, c2 = 0.f, c3 = 0.f;
    float c4 = 0.f, c5 = 0.f, c6 = 0.f, c7 = 0.f;
    int p = beg;
    for (; p + 1 < end; p += 2) {
        int s0 = csr[p], s1 = csr[p + 1];
        uint4 u0 = *(const uint4*)(zb + (size_t)s0 * 32 + l8);
        uint4 u1 = *(const uint4*)(zb + (size_t)s1 * 32 + l8);
        a0 += bflo(u0.x); a1 += bfhi(u0.x); a2 += bflo(u0.y); a3 += bfhi(u0.y);
        a4 += bflo(u0.z); a5 += bfhi(u0.z); a6 += bflo(u0.w); a7 += bfhi(u0.w);
        c0 += bflo(u1.x); c1 += bfhi(u1.x); c2 += bflo(u1.y); c3 += bfhi(u1.y);
        c4 += bflo(u1.z); c5 += bfhi(u1.z); c6 += bflo(u1.w); c7 += bfhi(u1.w);
    }
    if (p < end) {
        int s0 = csr[p];
        uint4 u0 = *(const uint4*)(zb + (size_t)s0 * 32 + l8);
        a0 += bflo(u0.x); a1 += bfhi(u0.x); a2 += bflo(u0.y); a3 += bfhi(u0.y);
        a4 += bflo(u0.z); a5 += bfhi(u0.z); a6 += bflo(u0.w); a7 += bfhi(u0.w);
    }
    float rec = 1.0f / (float)(end - beg + 1);
    float4 bb0 = *(const float4*)(b2 + l8);
    float4 bb1 = *(const float4*)(b2 + l8 + 4);
    float4 o0, o1;
    o0.x = (a0 + c0) * rec + bb0.x;
    o0.y = (a1 + c1) * rec + bb0.y;
    o0.z = (a2 + c2) * rec + bb0.z;
    o0.w = (a3 + c3) * rec + bb0.w;
    o1.x = (a4 + c4) * rec + bb1.x;
    o1.y = (a5 + c5) * rec + bb1.y;
    o1.z = (a6 + c6) * rec + bb1.z;
    o1.w = (a7 + c7) * rec + bb1.w;
    *(float4*)(out + (size_t)g * 32 + l8) = o0;
    *(float4*)(out + (size_t)g * 32 + l8 + 4) = o1;
}

// ===========================================================================
// GEMM2 via MFMA, zero LDS: zb = bf16(h1b @ W2)  (W2 fp32, in-reg convert)
// ===========================================================================
__global__ __launch_bounds__(256) void gemm2z_kernel(
    const unsigned short* __restrict__ h1b,
    const float* __restrict__ W2, unsigned short* __restrict__ zb)
{
    int t    = threadIdx.x;
    int wv   = t >> 6;
    int lane = t & 63;
    int quad = lane >> 4;
    int lc   = lane & 15;

    bf16x8 bfr[2][4];
    for (int ct = 0; ct < 2; ++ct)
        for (int ks = 0; ks < 4; ++ks) {
            bf16x8 tmp;
            #pragma unroll
            for (int j = 0; j < 8; ++j)
                tmp[j] = (short)f2bf(W2[(ks * 32 + quad * 8 + j) * 32 + ct * 16 + lc]);
            bfr[ct][ks] = tmp;
        }

    f32x4 acc[2][2];
    for (int rt = 0; rt < 2; ++rt)
        for (int ct = 0; ct < 2; ++ct)
            acc[rt][ct] = (f32x4){0.f, 0.f, 0.f, 0.f};

    int vb = blockIdx.x * 128 + wv * 32;
    for (int rt = 0; rt < 2; ++rt) {
        int row = vb + rt * 16 + lc;
        int vrow = (row < N_NODES) ? row : 0;
        #pragma unroll
        for (int ks = 0; ks < 4; ++ks) {
            bf16x8 af = *(const bf16x8*)(h1b + (size_t)vrow * 128 + ks * 32 + quad * 8);
            acc[rt][0] = __builtin_amdgcn_mfma_f32_16x16x32_bf16(af, bfr[0][ks], acc[rt][0], 0, 0, 0);
            acc[rt][1] = __builtin_amdgcn_mfma_f32_16x16x32_bf16(af, bfr[1][ks], acc[rt][1], 0, 0, 0);
        }
    }

    for (int rt = 0; rt < 2; ++rt)
        for (int ct = 0; ct < 2; ++ct)
            #pragma unroll
            for (int r = 0; r < 4; ++r) {
                int grow = vb + rt * 16 + quad * 4 + r;
                if (grow < N_NODES)
                    zb[(size_t)grow * 32 + ct * 16 + lc] = f2bf(acc[rt][ct][r]);
            }
}

// ===========================================================================
// FALLBACK PATH (ws too small): atomic scatter + fp32 GEMMs
// ===========================================================================
__global__ __launch_bounds__(256) void scatter_kernel(
    const float* __restrict__ x, const int* __restrict__ src,
    const int* __restrict__ dst, float* __restrict__ msg,
    float* __restrict__ deg, int nE)
{
    int tid  = blockIdx.x * 256 + threadIdx.x;
    int e    = tid >> 5;
    int lane = tid & 31;
    if (e >= nE) return;
    int s = src[e];
    int d = dst[e];
    if (deg != nullptr && lane == 0) atomicAdd(&deg[d], 1.0f);
    float4 v = *(const float4*)(x + (size_t)s * F_IN + lane * 4);
    float* mp = msg + (size_t)d * F_IN + lane * 4;
    atomicAdd(mp + 0, v.x);
    atomicAdd(mp + 1, v.y);
    atomicAdd(mp + 2, v.z);
    atomicAdd(mp + 3, v.w);
}

__global__ __launch_bounds__(256) void normalize_kernel(
    const float* __restrict__ self, const float* __restrict__ deg,
    float* __restrict__ msg)
{
    int idx = blockIdx.x * 256 + threadIdx.x;
    int v = idx >> 5;
    int c = (idx & 31) * 4;
    if (v >= N_NODES) return;
    float rec = 1.0f / (deg[v] + 1.0f);
    float4 m = *(const float4*)(msg  + (size_t)v * 128 + c);
    float4 s = *(const float4*)(self + (size_t)v * 128 + c);
    m.x = (m.x + s.x) * rec;
    m.y = (m.y + s.y) * rec;
    m.z = (m.z + s.z) * rec;
    m.w = (m.w + s.w) * rec;
    *(float4*)(msg + (size_t)v * 128 + c) = m;
}

__global__ __launch_bounds__(256) void gemm1_kernel(
    const float* __restrict__ msg, const float* __restrict__ W,
    const float* __restrict__ b, float* __restrict__ h)
{
    __shared__ float Wl[128 * 68];
    __shared__ float Rl[32 * 132];
    int t     = threadIdx.x;
    int vb    = blockIdx.x * 32;
    int jbase = blockIdx.y * 64;
    for (int i4 = t; i4 < 2048; i4 += 256) {
        int flat = i4 * 4;
        int k  = flat >> 6;
        int jj = flat & 63;
        *(float4*)(Wl + k * 68 + jj) = *(const float4*)(W + k * F_H + jbase + jj);
    }
    for (int i4 = t; i4 < 1024; i4 += 256) {
        int flat = i4 * 4;
        int r = flat >> 7;
        int k = flat & 127;
        int v = vb + r;
        float4 sv = (v < N_NODES) ? *(const float4*)(msg + (size_t)v * F_IN + k)
                                  : make_float4(0.f, 0.f, 0.f, 0.f);
        *(float4*)(Rl + r * 132 + k) = sv;
    }
    __syncthreads();
    int j0 = (t & 15) * 4;
    int r0 = (t >> 4) * 2;
    float acc[2][4] = {{0.f,0.f,0.f,0.f},{0.f,0.f,0.f,0.f}};
    for (int k = 0; k < 128; ++k) {
        float4 w = *(const float4*)(Wl + k * 68 + j0);
        float s0 = Rl[(r0    ) * 132 + k];
        float s1 = Rl[(r0 + 1) * 132 + k];
        acc[0][0] += s0 * w.x; acc[0][1] += s0 * w.y;
        acc[0][2] += s0 * w.z; acc[0][3] += s0 * w.w;
        acc[1][0] += s1 * w.x; acc[1][1] += s1 * w.y;
        acc[1][2] += s1 * w.z; acc[1][3] += s1 * w.w;
    }
    for (int i = 0; i < 2; ++i) {
        int v = vb + r0 + i;
        if (v >= N_NODES) continue;
        float4 o;
        o.x = acc[i][0] + b[jbase + j0 + 0];
        o.y = acc[i][1] + b[jbase + j0 + 1];
        o.z = acc[i][2] + b[jbase + j0 + 2];
        o.w = acc[i][3] + b[jbase + j0 + 3];
        o.x = (o.x >= 0.f) ? o.x : NEG_SLOPE * o.x;
        o.y = (o.y >= 0.f) ? o.y : NEG_SLOPE * o.y;
        o.z = (o.z >= 0.f) ? o.z : NEG_SLOPE * o.z;
        o.w = (o.w >= 0.f) ? o.w : NEG_SLOPE * o.w;
        *(float4*)(h + (size_t)v * F_H + jbase + j0) = o;
    }
}

__global__ __launch_bounds__(256) void gemm2_kernel(
    const float* __restrict__ msg, const float* __restrict__ W,
    const float* __restrict__ b, float* __restrict__ out)
{
    __shared__ float Wl[128 * 36];
    __shared__ float Rl[64 * 132];
    int t  = threadIdx.x;
    int vb = blockIdx.x * 64;
    for (int i4 = t; i4 < 1024; i4 += 256) {
        int flat = i4 * 4;
        int k  = flat >> 5;
        int jj = flat & 31;
        *(float4*)(Wl + k * 36 + jj) = *(const float4*)(W + k * F_OUT + jj);
    }
    for (int i4 = t; i4 < 2048; i4 += 256) {
        int flat = i4 * 4;
        int r = flat >> 7;
        int k = flat & 127;
        int v = vb + r;
        float4 sv = (v < N_NODES) ? *(const float4*)(msg + (size_t)v * F_H + k)
                                  : make_float4(0.f, 0.f, 0.f, 0.f);
        *(float4*)(Rl + r * 132 + k) = sv;
    }
    __syncthreads();
    int j0 = (t & 7) * 4;
    int r0 = (t >> 3) * 2;
    float acc[2][4] = {{0.f,0.f,0.f,0.f},{0.f,0.f,0.f,0.f}};
    for (int k = 0; k < 128; ++k) {
        float4 w = *(const float4*)(Wl + k * 36 + j0);
        float s0 = Rl[(r0    ) * 132 + k];
        float s1 = Rl[(r0 + 1) * 132 + k];
        acc[0][0] += s0 * w.x; acc[0][1] += s0 * w.y;
        acc[0][2] += s0 * w.z; acc[0][3] += s0 * w.w;
        acc[1][0] += s1 * w.x; acc[1][1] += s1 * w.y;
        acc[1][2] += s1 * w.z; acc[1][3] += s1 * w.w;
    }
    for (int i = 0; i < 2; ++i) {
        int v = vb + r0 + i;
        if (v >= N_NODES) continue;
        float4 o;
        o.x = acc[i][0] + b[j0 + 0];
        o.y = acc[i][1] + b[j0 + 1];
        o.z = acc[i][2] + b[j0 + 2];
        o.w = acc[i][3] + b[j0 + 3];
        *(float4*)(out + (size_t)v * F_OUT + j0) = o;
    }
}

// ===========================================================================
// Launch
// ===========================================================================
extern "C" void kernel_launch(void* const* d_in, const int* in_sizes, int n_in,
                              void* d_out, int out_size, void* d_ws, size_t ws_size,
                              hipStream_t stream)
{
    const float* x     = (const float*)d_in[0];
    const int*   edges = (const int*)d_in[1];
    const float* W1    = (const float*)d_in[2];
    const float* b1    = (const float*)d_in[3];
    const float* W2    = (const float*)d_in[4];
    const float* b2    = (const float*)d_in[5];
    float* out = (float*)d_out;

    const int* src = edges;
    const int* dst = edges + N_EDGES;

    const size_t INT_WORDS = 256ull + 50432ull + 800000ull + 153664ull + 800000ull;
    const size_t SHORTS = 6400000ull + 6400000ull + 1600000ull;
    const size_t FAST_BYTES = INT_WORDS * 4 + SHORTS * 2;   // ~36 MB

    if (ws_size >= FAST_BYTES) {
        // ---- fast path layout ----
        int*   bucket_total = (int*)d_ws;                      // [256]
        int*   row_ptr      = bucket_total + 256;              // [50432]
        int*   csr          = row_ptr + 50432;                 // [800000]
        int*   counts       = csr + 800000;                    // [153664]
        unsigned int* bins  = (unsigned int*)(counts + 153664);// [800000]
        unsigned short* yb  = (unsigned short*)(bins + 800000);// [6.4M]
        unsigned short* h1b = yb + 6400000;                    // [6.4M]
        unsigned short* zb  = h1b + 6400000;                   // [1.6M]

        // 1. Fused: edge histogram + MFMA y = x@W1 (bf16)
        hist_gemm1_kernel<<<EDGE_BLOCKS + GEMM1_BLOCKS, 256, 0, stream>>>(
            dst, counts, x, W1, yb);
        // 2-4. CSR build (no global atomics, no memsets)
        scan_cols_kernel<<<NBUCKET, 256, 0, stream>>>(counts, bucket_total);
        bin_kernel<<<EDGE_BLOCKS, 256, 0, stream>>>(src, dst, counts,
                                                    bucket_total, bins);
        bucket_sort_kernel<<<NBUCKET, 256, 0, stream>>>(bins, bucket_total,
                                                        row_ptr, csr);
        // 5. Layer-1 aggregate (full-row gathers, single pass — R10 form)
        aggregate128_kernel<<<(N_NODES * 16 + 255) / 256, 256, 0, stream>>>(
            yb, row_ptr, csr, b1, h1b);
        // 6. z = h1 @ W2 via MFMA (bf16 in/out, no LDS)
        gemm2z_kernel<<<GEMM2_BLOCKS, 256, 0, stream>>>(h1b, W2, zb);
        // 7. Layer-2 aggregate w/ fused bias, fp32 out
        aggregate32_kernel<<<(N_NODES * 4 + 255) / 256, 256, 0, stream>>>(
            zb, row_ptr, csr, b2, out);
    } else {
        // ---- fallback: atomic scatter (fp32 end-to-end) ----
        float* deg = (float*)d_ws;
        float* msg = deg + 50176;
        float* h1  = msg + (size_t)N_NODES * F_H;

        hipMemsetAsync(d_ws, 0, (50176 + (size_t)N_NODES * F_H) * sizeof(float), stream);
        int sb = (N_EDGES * 32 + 255) / 256;
        int nb = (N_NODES * 32 + 255) / 256;

        scatter_kernel<<<sb, 256, 0, stream>>>(x, src, dst, msg, deg, N_EDGES);
        normalize_kernel<<<nb, 256, 0, stream>>>(x, deg, msg);
        gemm1_kernel<<<dim3((N_NODES + 31) / 32, 2), 256, 0, stream>>>(msg, W1, b1, h1);

        hipMemsetAsync(msg, 0, (size_t)N_NODES * F_H * sizeof(float), stream);
        scatter_kernel<<<sb, 256, 0, stream>>>(h1, src, dst, msg, nullptr, N_EDGES);
        normalize_kernel<<<nb, 256, 0, stream>>>(h1, deg, msg);
        gemm2_kernel<<<(N_NODES + 63) / 64, 256, 0, stream>>>(msg, W2, b2, out);
    }
}